// Round 7
// baseline (262.175 us; speedup 1.0000x reference)
//
#include <hip/hip_runtime.h>
#include <math.h>

// Problem constants (match reference setup_inputs)
constexpr int B = 128, T = 128, F = 2048, KW = 5;
#define ALPHA 0.9f
#define BETA  0.1f
#define DECAY 0.9f
#define GAMMA 0.5f

constexpr int TG  = 16;    // t-rows per staged group
constexpr int NG  = T / TG;
constexpr int BLK = 256;   // threads per block == f-tile width

// Async global->LDS, 16B per lane. LDS dest is wave-uniform base + lane*16
// (HW semantic); global src is per-lane. Zero VGPR cost -> the compiler
// cannot collapse this prefetch (unlike the R4/R6 register ring, which it
// sank back to load->use, VGPR=48 evidence).
__device__ __forceinline__ void load_lds16(const float* gsrc, float* lds) {
    __builtin_amdgcn_global_load_lds(
        (const __attribute__((address_space(1))) unsigned int*)gsrc,
        (__attribute__((address_space(3))) unsigned int*)lds,
        16, 0, 0);
}

// Full-range atan, max err ~2e-6 rad: odd minimax poly on [-1,1] with
// v_rcp_f32 range reduction. Replaces ocml atanf (~2x instrs, ~2x chain).
__device__ __forceinline__ float atan_fast(float z) {
    float az  = __builtin_fabsf(z);
    float inv = __builtin_amdgcn_rcpf(az);
    bool  big = az > 1.0f;
    float u   = big ? inv : az;
    float u2  = u * u;
    float p   = fmaf(u2, -0.01172120f, 0.05265332f);
    p = fmaf(u2, p, -0.11643287f);
    p = fmaf(u2, p,  0.19354346f);
    p = fmaf(u2, p, -0.33262347f);
    p = fmaf(u2, p,  0.99997726f);
    float r = u * p;
    r = big ? (1.57079632679f - r) : r;
    return copysignf(r, z);
}

// Block = (b, 256-wide f-tile). 1024 blocks, 16 waves/CU (occupancy cap 50%).
// pass 1: register 8-deep streaming sum -> analytic conv-sum -> scale
// pass 2: LDS double-buffered staging (async DMA) + rolling conv + LIF
__global__ __launch_bounds__(256, 4) void lif_fused_kernel(
    const float* __restrict__ x,        // [B,T,F]
    const float* __restrict__ thr0p,    // scalar
    const float* __restrict__ convw,    // [1,1,KW]
    const float* __restrict__ convb,    // [1]
    const float* __restrict__ sattn,    // [1]
    float* __restrict__ out)            // [B*T*F] spikes ++ [B*F] mem
{
    const int b    = blockIdx.x >> 3;          // 8 f-tiles per batch row
    const int f0   = (blockIdx.x & 7) * BLK;
    const int fg   = f0 + threadIdx.x;
    const int lane = threadIdx.x & 63;
    const int wid  = threadIdx.x >> 6;         // 4 waves per block

    __shared__ float buf[2][TG][BLK];          // 32 KiB

    const float w0 = convw[0], w1 = convw[1], w2 = convw[2],
                w3 = convw[3], w4 = convw[4];
    const float cb   = convb[0];
    const float thr0 = thr0p[0];
    const float sa   = sattn[0];

    const float* xbase = x + (size_t)b * T * F;
    const float* xp    = xbase + fg;

    // ---- pass 1: sum of x over t (8 partial sums, 8 loads in flight) ----
    float s0=0.f,s1=0.f,s2=0.f,s3=0.f,s4=0.f,s5=0.f,s6=0.f,s7=0.f;
#pragma unroll 2
    for (int t = 0; t < T; t += 8) {
        s0 += xp[(size_t)(t+0)*F]; s1 += xp[(size_t)(t+1)*F];
        s2 += xp[(size_t)(t+2)*F]; s3 += xp[(size_t)(t+3)*F];
        s4 += xp[(size_t)(t+4)*F]; s5 += xp[(size_t)(t+5)*F];
        s6 += xp[(size_t)(t+6)*F]; s7 += xp[(size_t)(t+7)*F];
    }
    const float sx = ((s0+s1)+(s2+s3)) + ((s4+s5)+(s6+s7));

    // edge values (L2/L3-warm re-reads)
    const float e0  = xp[0];
    const float e1  = xp[(size_t)F];
    const float em2 = xp[(size_t)(T-2)*F];
    const float em1 = xp[(size_t)(T-1)*F];

    // sum_t conv[t] = W*sum_t x - (w3+w4)x[0] - w4 x[1] - w0 x[T-2] - (w0+w1)x[T-1] + T*cb
    const float W = ((w0+w1)+(w2+w3)) + w4;
    const float csum = fmaf(W, sx, (float)T * cb)
                     - (w3+w4)*e0 - w4*e1 - w0*em2 - (w0+w1)*em1;

    // ---- spatial attention gate ----
    const float z     = sa * (csum * (1.0f/(float)T));
    const float watt  = 1.0f / (1.0f + expf(-z));
    const float scale = 1.0f + GAMMA * watt;

    // ---- pass 2: staged rolling conv + LIF ----
    const float PIH    = 1.57079632679f;        // pi/2
    const float INV2PI = 0.15915494309f;        // 1/(2*pi)
    const float thc    = (1.0f - ALPHA) * thr0;

    float mem = 0.f, thr = thr0;
    float h1 = 0.f, h2 = 0.f;
    // window regs: a=x[t-2], bb=x[t-1], c=x[t], d=x[t+1]
    float a = 0.f, bb = 0.f, c = e0, d = e1;

    float* sp = out + (size_t)b * T * F + fg;
    float* mp = out + (size_t)B * T * F + (size_t)b * F + fg;

    // group g stages e-rows t = 16g+2 .. 16g+17 (the x[t+2] stream)
    auto stage = [&](int g, int pb) {
#pragma unroll
        for (int r4 = 0; r4 < 4; ++r4) {
            const int row = (wid << 2) | r4;    // wave w owns rows 4w..4w+3
            const int te  = g * TG + 2 + row;
            if (te < T)
                load_lds16(xbase + (size_t)te * F + f0 + (lane << 2),
                           &buf[pb][row][0]);
        }
        if (g == NG - 1) {                      // zero pad t=128,129
            buf[pb][TG-2][threadIdx.x] = 0.0f;
            buf[pb][TG-1][threadIdx.x] = 0.0f;
        }
    };

    auto lif_step = [&](int t, float e) {
        float ct = fmaf(w0, a, fmaf(w1, bb, fmaf(w2, c,
                   fmaf(w3, d, fmaf(w4, e, cb)))));
        mem = fmaf(DECAY, mem, ct * scale);
        float sarg  = PIH * (mem - thr);
        float spike = fmaf(atan_fast(sarg), INV2PI, 0.25f);
        float avg   = (h1 + h2 + spike) * (1.0f/3.0f);
        h1 = h2; h2 = spike;
        thr = fmaf(ALPHA, thr, fmaf(BETA, avg, thc));
        mem = fmaf(-spike, thr, mem);
        __builtin_nontemporal_store(spike, sp + (size_t)t * F);
        a = bb; bb = c; c = d; d = e;
    };

    stage(0, 0);
    __syncthreads();                            // group 0 staged
    for (int g = 0; g < NG; ++g) {
        if (g + 1 < NG) stage(g + 1, (g + 1) & 1);  // async prefetch
        const int pb = g & 1;
#pragma unroll
        for (int r = 0; r < TG; ++r) {
            float e = buf[pb][r][threadIdx.x];      // ds_read, 2-way alias = free
            lif_step(g * TG + r, e);
        }
        __syncthreads();                        // drains vmcnt: g+1 landed
    }

    __builtin_nontemporal_store(mem, mp);
}

extern "C" void kernel_launch(void* const* d_in, const int* in_sizes, int n_in,
                              void* d_out, int out_size, void* d_ws, size_t ws_size,
                              hipStream_t stream) {
    const float* x     = (const float*)d_in[0];
    const float* thr0  = (const float*)d_in[1];
    const float* convw = (const float*)d_in[2];
    const float* convb = (const float*)d_in[3];
    const float* sattn = (const float*)d_in[4];
    float* out = (float*)d_out;

    const int grid = B * (F / BLK);     // 1024 blocks: (b, f-tile)
    lif_fused_kernel<<<grid, BLK, 0, stream>>>(x, thr0, convw, convb, sattn, out);
}

// Round 9
// 260.951 us; speedup vs baseline: 1.0047x; 1.0047x over previous
//
#include <hip/hip_runtime.h>
#include <math.h>

// Problem constants (match reference setup_inputs)
constexpr int B = 128, T = 128, F = 2048, KW = 5;
#define ALPHA 0.9f
#define BETA  0.1f
#define DECAY 0.9f
#define GAMMA 0.5f

constexpr int BLK = 512;   // threads per block == f-tile width (2KB bursts)
constexpr int TG  = 16;    // t-rows per staged group (32KB DMA per group)
constexpr int NG  = T / TG;

// Async global->LDS, 16B per lane (zero-VGPR staging; compiler can't sink it).
__device__ __forceinline__ void load_lds16(const float* gsrc, float* lds) {
    __builtin_amdgcn_global_load_lds(
        (const __attribute__((address_space(1))) unsigned int*)gsrc,
        (__attribute__((address_space(3))) unsigned int*)lds,
        16, 0, 0);
}

// Full-range atan, max err ~2e-6 rad (validated R6: absmax unchanged).
__device__ __forceinline__ float atan_fast(float z) {
    float az  = __builtin_fabsf(z);
    float inv = __builtin_amdgcn_rcpf(az);
    bool  big = az > 1.0f;
    float u   = big ? inv : az;
    float u2  = u * u;
    float p   = fmaf(u2, -0.01172120f, 0.05265332f);
    p = fmaf(u2, p, -0.11643287f);
    p = fmaf(u2, p,  0.19354346f);
    p = fmaf(u2, p, -0.33262347f);
    p = fmaf(u2, p,  0.99997726f);
    float r = u * p;
    r = big ? (1.57079632679f - r) : r;
    return copysignf(r, z);
}

// R7 theory: all prior variants (91-103us) pinned at ~2.9 TB/s with every
// on-chip pipe <40% -> DRAM pattern-limited (1KB fragments strided 8KB,
// fine-grained read/write interleave). This version widens every burst:
// 512-wide f-tile => 2KB per t-row for pass-1 reads, DMA reads, and spike
// writes; 32KB grouped DMA bursts; barrier-phased so reads and writes hit
// the controller in large alternating batches. 2 blocks/CU, 16 waves/CU.
__global__ __launch_bounds__(BLK, 4) void lif_fused_kernel(
    const float* __restrict__ x,        // [B,T,F]
    const float* __restrict__ thr0p,    // scalar
    const float* __restrict__ convw,    // [1,1,KW]
    const float* __restrict__ convb,    // [1]
    const float* __restrict__ sattn,    // [1]
    float* __restrict__ out)            // [B*T*F] spikes ++ [B*F] mem
{
    const int b    = blockIdx.x >> 2;          // 4 f-tiles per batch row
    const int f0   = (blockIdx.x & 3) * BLK;
    const int tid  = threadIdx.x;
    const int fg   = f0 + tid;
    const int lane = tid & 63;
    const int wid  = tid >> 6;                 // 8 waves per block

    __shared__ float rbuf[2][TG][BLK];         // 64 KiB double-buffered

    const float w0 = convw[0], w1 = convw[1], w2 = convw[2],
                w3 = convw[3], w4 = convw[4];
    const float cb   = convb[0];
    const float thr0 = thr0p[0];
    const float sa   = sattn[0];

    const float* xbase = x + (size_t)b * T * F;
    const float* xp    = xbase + fg;

    // ---- pass 1: sum of x over t (8 partial sums, 8 loads in flight) ----
    float s0=0.f,s1=0.f,s2=0.f,s3=0.f,s4=0.f,s5=0.f,s6=0.f,s7=0.f;
#pragma unroll 2
    for (int t = 0; t < T; t += 8) {
        s0 += xp[(size_t)(t+0)*F]; s1 += xp[(size_t)(t+1)*F];
        s2 += xp[(size_t)(t+2)*F]; s3 += xp[(size_t)(t+3)*F];
        s4 += xp[(size_t)(t+4)*F]; s5 += xp[(size_t)(t+5)*F];
        s6 += xp[(size_t)(t+6)*F]; s7 += xp[(size_t)(t+7)*F];
    }
    const float sx = ((s0+s1)+(s2+s3)) + ((s4+s5)+(s6+s7));

    // edge values (L2/L3-warm re-reads)
    const float e0  = xp[0];
    const float e1  = xp[(size_t)F];
    const float em2 = xp[(size_t)(T-2)*F];
    const float em1 = xp[(size_t)(T-1)*F];

    // sum_t conv[t] = W*sum_t x - (w3+w4)x[0] - w4 x[1] - w0 x[T-2] - (w0+w1)x[T-1] + T*cb
    const float W = ((w0+w1)+(w2+w3)) + w4;
    const float csum = fmaf(W, sx, (float)T * cb)
                     - (w3+w4)*e0 - w4*e1 - w0*em2 - (w0+w1)*em1;

    // ---- spatial attention gate ----
    const float z     = sa * (csum * (1.0f/(float)T));
    const float watt  = 1.0f / (1.0f + expf(-z));
    const float scale = 1.0f + GAMMA * watt;

    // ---- pass 2: group-staged rolling conv + LIF ----
    const float PIH    = 1.57079632679f;        // pi/2
    const float INV2PI = 0.15915494309f;        // 1/(2*pi)
    const float thc    = (1.0f - ALPHA) * thr0;

    float mem = 0.f, thr = thr0;
    float h1 = 0.f, h2 = 0.f;
    // window regs: a=x[t-2], bb=x[t-1], c=x[t], d=x[t+1]
    float a = 0.f, bb = 0.f, c = e0, d = e1;

    float* sp = out + (size_t)b * T * F + fg;
    float* mp = out + (size_t)B * T * F + (size_t)b * F + fg;

    // group g stages e-rows te = 16g+2 .. 16g+17 (the x[t+2] stream).
    // 32 chunks of 1KB; wave w takes chunks 4w..4w+3 -> rows 2w,2w+1.
    auto stage = [&](int g, int pb) {
#pragma unroll
        for (int k = 0; k < 4; ++k) {
            const int row = (wid << 1) | (k >> 1);
            const int q   = k & 1;             // 256-float half of the row
            const int te  = TG * g + 2 + row;
            if (te < T)
                load_lds16(xbase + (size_t)te * F + f0 + q * 256 + (lane << 2),
                           &rbuf[pb][row][q * 256]);
        }
        if (g == NG - 1) {                     // zero pad te = 128,129
            rbuf[pb][TG-2][tid] = 0.0f;
            rbuf[pb][TG-1][tid] = 0.0f;
        }
    };

    auto lif_step = [&](int t, float e) {
        float ct = fmaf(w0, a, fmaf(w1, bb, fmaf(w2, c,
                   fmaf(w3, d, fmaf(w4, e, cb)))));
        mem = fmaf(DECAY, mem, ct * scale);
        float sarg  = PIH * (mem - thr);
        float spike = fmaf(atan_fast(sarg), INV2PI, 0.25f);
        float avg   = (h1 + h2 + spike) * (1.0f/3.0f);
        h1 = h2; h2 = spike;
        thr = fmaf(ALPHA, thr, fmaf(BETA, avg, thc));
        mem = fmaf(-spike, thr, mem);
        __builtin_nontemporal_store(spike, sp + (size_t)t * F);
        a = bb; bb = c; c = d; d = e;
    };

    stage(0, 0);
    __syncthreads();                           // group 0 staged (vmcnt drained)
    for (int g = 0; g < NG; ++g) {
        if (g + 1 < NG) stage(g + 1, (g + 1) & 1);  // async 32KB prefetch
        const int pb = g & 1;
#pragma unroll
        for (int r = 0; r < TG; ++r) {
            float e = rbuf[pb][r][tid];        // conflict-free (2-way alias)
            lif_step(g * TG + r, e);
        }
        __syncthreads();                       // drains DMA for group g+1
    }

    __builtin_nontemporal_store(mem, mp);
}

extern "C" void kernel_launch(void* const* d_in, const int* in_sizes, int n_in,
                              void* d_out, int out_size, void* d_ws, size_t ws_size,
                              hipStream_t stream) {
    const float* x     = (const float*)d_in[0];
    const float* thr0  = (const float*)d_in[1];
    const float* convw = (const float*)d_in[2];
    const float* convb = (const float*)d_in[3];
    const float* sattn = (const float*)d_in[4];
    float* out = (float*)d_out;

    const int grid = B * (F / BLK);     // 512 blocks: (b, f-tile)
    lif_fused_kernel<<<grid, BLK, 0, stream>>>(x, thr0, convw, convb, sattn, out);
}

// Round 11
// 252.092 us; speedup vs baseline: 1.0400x; 1.0351x over previous
//
#include <hip/hip_runtime.h>
#include <math.h>

// Problem constants (match reference setup_inputs)
constexpr int B = 128, T = 128, F = 2048, KW = 5;
#define ALPHA 0.9f
#define BETA  0.1f
#define DECAY 0.9f
#define GAMMA 0.5f

// native clang vector type (nontemporal builtin rejects HIP float2)
typedef float v2f __attribute__((ext_vector_type(2)));

// Full-range atan, max err ~2e-6 rad (validated R6/R7: absmax unchanged).
__device__ __forceinline__ float atan_fast(float z) {
    float az  = __builtin_fabsf(z);
    float inv = __builtin_amdgcn_rcpf(az);
    bool  big = az > 1.0f;
    float u   = big ? inv : az;
    float u2  = u * u;
    float p   = fmaf(u2, -0.01172120f, 0.05265332f);
    p = fmaf(u2, p, -0.11643287f);
    p = fmaf(u2, p,  0.19354346f);
    p = fmaf(u2, p, -0.33262347f);
    p = fmaf(u2, p,  0.99997726f);
    float r = u * p;
    r = big ? (1.57079632679f - r) : r;
    return copysignf(r, z);
}

// Structure = measured-best v2 (float2, 2 series/thread, 93us) + fast-atan.
// R9 change: XCD-aware block remap. Default dispatch round-robins consecutive
// blockIdx across the 8 XCDs, so the 4 blocks covering one (b,t) 8KB DRAM row
// sit on 4 different L2s and drift apart -> every DRAM row is visited 4x by
// 4 uncoordinated writers/readers (~45% controller efficiency, the measured
// 2.9 TB/s plateau across 5 structural variants). Remap: xcd = blk&7 owns
// b-rows [16*xcd,16*xcd+16); its 4 consecutive slots = the 4 f-chunks of one
// b-row -> same L2, temporally adjacent => full-row read locality + write
// combining. NT stores kept (FETCH==x verified: keeps x L3-resident).
__global__ __launch_bounds__(256) void lif_fused_kernel(
    const float* __restrict__ x,        // [B,T,F]
    const float* __restrict__ thr0p,    // scalar
    const float* __restrict__ convw,    // [1,1,KW]
    const float* __restrict__ convb,    // [1]
    const float* __restrict__ sattn,    // [1]
    float* __restrict__ out)            // [B*T*F] spikes ++ [B*F] mem
{
    // ---- XCD-locality block remap (bijective on 0..511) ----
    const int raw    = blockIdx.x;       // 512 blocks
    const int xcd    = raw & 7;          // presumed XCD id (round-robin)
    const int slot   = raw >> 3;         // 0..63 within XCD
    const int b      = xcd * 16 + (slot >> 2);   // 16 b-rows per XCD
    const int fchunk = slot & 3;                 // 4 f-chunks of this b-row
    const int f      = fchunk * 512 + (int)threadIdx.x * 2;

    const float w0 = convw[0], w1 = convw[1], w2 = convw[2],
                w3 = convw[3], w4 = convw[4];
    const float cb   = convb[0];
    const float thr0 = thr0p[0];
    const float sa   = sattn[0];

    const float* xp = x + (size_t)b * T * F + f;

    // ---- pass 1: sum of x over t (8 partial sums, 8 loads in flight) ----
    v2f s0 = {0.f,0.f}, s1 = {0.f,0.f}, s2 = {0.f,0.f}, s3 = {0.f,0.f},
        s4 = {0.f,0.f}, s5 = {0.f,0.f}, s6 = {0.f,0.f}, s7 = {0.f,0.f};
#pragma unroll 2
    for (int t = 0; t < T; t += 8) {
        v2f v0 = *(const v2f*)(xp + (size_t)(t + 0) * F);
        v2f v1 = *(const v2f*)(xp + (size_t)(t + 1) * F);
        v2f v2 = *(const v2f*)(xp + (size_t)(t + 2) * F);
        v2f v3 = *(const v2f*)(xp + (size_t)(t + 3) * F);
        v2f v4 = *(const v2f*)(xp + (size_t)(t + 4) * F);
        v2f v5 = *(const v2f*)(xp + (size_t)(t + 5) * F);
        v2f v6 = *(const v2f*)(xp + (size_t)(t + 6) * F);
        v2f v7 = *(const v2f*)(xp + (size_t)(t + 7) * F);
        s0 += v0; s1 += v1; s2 += v2; s3 += v3;
        s4 += v4; s5 += v5; s6 += v6; s7 += v7;
    }
    v2f sx = ((s0 + s1) + (s2 + s3)) + ((s4 + s5) + (s6 + s7));

    // edge values (L2/L3-warm re-reads)
    v2f e0  = *(const v2f*)(xp);                      // x[0]
    v2f e1  = *(const v2f*)(xp + (size_t)F);          // x[1]
    v2f em2 = *(const v2f*)(xp + (size_t)(T - 2) * F);// x[T-2]
    v2f em1 = *(const v2f*)(xp + (size_t)(T - 1) * F);// x[T-1]

    // sum_t conv[t] = W*sum_t x - (w3+w4)x[0] - w4 x[1] - w0 x[T-2] - (w0+w1)x[T-1] + T*cb
    const float W = ((w0 + w1) + (w2 + w3)) + w4;
    v2f csum;
    csum.x = fmaf(W, sx.x, (float)T * cb)
           - (w3 + w4) * e0.x - w4 * e1.x - w0 * em2.x - (w0 + w1) * em1.x;
    csum.y = fmaf(W, sx.y, (float)T * cb)
           - (w3 + w4) * e0.y - w4 * e1.y - w0 * em2.y - (w0 + w1) * em1.y;

    // ---- spatial attention gate ----
    v2f scale;
    {
        float zx = sa * (csum.x * (1.0f / (float)T));
        float zy = sa * (csum.y * (1.0f / (float)T));
        scale.x = 1.0f + GAMMA * (1.0f / (1.0f + expf(-zx)));
        scale.y = 1.0f + GAMMA * (1.0f / (1.0f + expf(-zy)));
    }

    // ---- pass 2: rolling conv + LIF recurrence ----
    const float PIH    = 1.57079632679f;        // pi/2
    const float INV2PI = 0.15915494309f;        // 1/(2*pi)
    const float thc    = (1.0f - ALPHA) * thr0;

    v2f mem = {0.f, 0.f};
    v2f thr = {thr0, thr0};
    v2f h1 = {0.f, 0.f}, h2 = {0.f, 0.f};
    // window regs: a=x[t-2], bb=x[t-1], c=x[t], d=x[t+1]
    v2f a = {0.f, 0.f}, bb = {0.f, 0.f}, c = e0, d = e1;

    float* sp = out + (size_t)b * T * F + f;                  // spikes [B,T,F]
    float* mp = out + (size_t)B * T * F + (size_t)b * F + f;  // mem [B,F]

    auto lif_step = [&](int t, v2f e) {
        float cx = fmaf(w0, a.x, fmaf(w1, bb.x, fmaf(w2, c.x,
                   fmaf(w3, d.x, fmaf(w4, e.x, cb)))));
        float cy = fmaf(w0, a.y, fmaf(w1, bb.y, fmaf(w2, c.y,
                   fmaf(w3, d.y, fmaf(w4, e.y, cb)))));
        mem.x = fmaf(DECAY, mem.x, cx * scale.x);
        mem.y = fmaf(DECAY, mem.y, cy * scale.y);
        float spx = fmaf(atan_fast(PIH * (mem.x - thr.x)), INV2PI, 0.25f);
        float spy = fmaf(atan_fast(PIH * (mem.y - thr.y)), INV2PI, 0.25f);
        float avx = (h1.x + h2.x + spx) * (1.0f / 3.0f);
        float avy = (h1.y + h2.y + spy) * (1.0f / 3.0f);
        h1 = h2; h2.x = spx; h2.y = spy;
        thr.x = fmaf(ALPHA, thr.x, fmaf(BETA, avx, thc));
        thr.y = fmaf(ALPHA, thr.y, fmaf(BETA, avy, thc));
        mem.x = fmaf(-spx, thr.x, mem.x);
        mem.y = fmaf(-spy, thr.y, mem.y);
        v2f spv = {spx, spy};
        __builtin_nontemporal_store(spv, (v2f*)(sp + (size_t)t * F));
        a = bb; bb = c; c = d; d = e;
    };

#pragma unroll 8
    for (int t = 0; t < T - 2; ++t) {
        v2f e = *(const v2f*)(xp + (size_t)(t + 2) * F);
        lif_step(t, e);
    }
    lif_step(T - 2, (v2f){0.f, 0.f});   // e = 0 (zero pad)
    lif_step(T - 1, (v2f){0.f, 0.f});   // d = e = 0

    __builtin_nontemporal_store(mem, (v2f*)mp);
}

extern "C" void kernel_launch(void* const* d_in, const int* in_sizes, int n_in,
                              void* d_out, int out_size, void* d_ws, size_t ws_size,
                              hipStream_t stream) {
    const float* x     = (const float*)d_in[0];
    const float* thr0  = (const float*)d_in[1];
    const float* convw = (const float*)d_in[2];
    const float* convb = (const float*)d_in[3];
    const float* sattn = (const float*)d_in[4];
    float* out = (float*)d_out;

    const int total = B * F / 2;        // one thread per 2 (b,f) series
    const int block = 256;
    const int grid  = total / block;    // 512 blocks

    lif_fused_kernel<<<grid, block, 0, stream>>>(x, thr0, convw, convb, sattn, out);
}